// Round 1
// baseline (270.494 us; speedup 1.0000x reference)
//
#include <hip/hip_runtime.h>
#include <cstdint>
#include <cmath>

typedef unsigned short u16;
typedef short bf16x8 __attribute__((ext_vector_type(8)));
typedef float f32x4 __attribute__((ext_vector_type(4)));

#define T_DIM 2048
#define B_DIM 16
#define CIN 512
#define COUT 512
#define KIN 1536
#define NROWS (T_DIM * B_DIM)        /* 32768 */
#define UROWS ((T_DIM + 2) * B_DIM)  /* 32800 */

__device__ __forceinline__ u16 f2bf(float f) {
  unsigned u = __builtin_bit_cast(unsigned, f);
  u = (u + 0x7FFFu + ((u >> 16) & 1u)) >> 16;   // RNE
  return (u16)u;
}

typedef __attribute__((address_space(3))) unsigned int as3u32;
typedef __attribute__((address_space(1))) unsigned int as1u32;

// async global->LDS, 16B per lane; lds must be the wave-uniform base.
__device__ __forceinline__ void gload16(const u16* g, const u16* lds) {
#if __has_builtin(__builtin_amdgcn_global_load_lds)
  __builtin_amdgcn_global_load_lds((as1u32*)(uintptr_t)g,
                                   (as3u32*)(unsigned)(uintptr_t)lds, 16, 0, 0);
#else
  unsigned lane = __lane_id();
  ((uint4*)lds)[lane] = *(const uint4*)g;
#endif
}

// ---- K0: column inv-norms of weight_v [KIN, COUT] over axis 0 ----
__global__ void k_colnorm(const float* __restrict__ wv, float* __restrict__ invn) {
  int o = blockIdx.x;
  int lane = threadIdx.x;  // 64
  float s = 0.f;
#pragma unroll
  for (int r = 0; r < KIN / 64; ++r) {
    float v = wv[(size_t)(r * 64 + lane) * COUT + o];
    s += v * v;
  }
#pragma unroll
  for (int d = 1; d < 64; d <<= 1) s += __shfl_xor(s, d);
  if (lane == 0) invn[o] = 1.f / fmaxf(sqrtf(s), 1e-15f);
}

// ---- K1: W^T bf16: wt[o][i] = wv[i][o] * invn[o] ----
__global__ void k_wt(const float* __restrict__ wv, const float* __restrict__ invn,
                     u16* __restrict__ wt) {
  __shared__ float tile[64][65];
  int i0 = blockIdx.x * 64;
  int o0 = blockIdx.y * 64;
  int tx = threadIdx.x & 63, ty = threadIdx.x >> 6;  // 256 thr
  for (int r = ty; r < 64; r += 4)
    tile[r][tx] = wv[(size_t)(i0 + r) * COUT + o0 + tx];
  __syncthreads();
  for (int r = ty; r < 64; r += 4) {
    float inv = invn[o0 + r];
    wt[(size_t)(o0 + r) * KIN + i0 + tx] = f2bf(tile[tx][r] * inv);
  }
}

// ---- K2: u = logmap0(x)*BETA_RATIO -> bf16 [UROWS,512]; nsq fp32 per row ----
__global__ void k_logmap(const float* __restrict__ x, u16* __restrict__ U,
                         float* __restrict__ nsq, float beta_ratio) {
  int row = blockIdx.x;        // 0..32799 = t_pad*16 + b
  int t = row >> 4;
  int lane = threadIdx.x;      // 64
  uint4* urow = (uint4*)(U + (size_t)row * CIN);
  if (t == 0 || t == T_DIM + 1) {
    uint4 z; z.x = z.y = z.z = z.w = 0u;
    urow[lane] = z;
    if (lane == 0) nsq[row] = 0.f;
    return;
  }
  const float4* xr = (const float4*)(x + (size_t)(row - 16) * CIN);
  float4 a = xr[lane * 2];
  float4 b = xr[lane * 2 + 1];
  float s = a.x*a.x + a.y*a.y + a.z*a.z + a.w*a.w
          + b.x*b.x + b.y*b.y + b.z*b.z + b.w*b.w;
#pragma unroll
  for (int d = 1; d < 64; d <<= 1) s += __shfl_xor(s, d);
  float r = sqrtf(s);
  float yn = fmaxf(r, 1e-15f);
  float arg = fminf(yn, 1.0f - 1e-7f);
  float f = atanhf(arg) / yn * beta_ratio;
  union { u16 h[8]; uint4 v; } pk;
  pk.h[0] = f2bf(a.x * f); pk.h[1] = f2bf(a.y * f);
  pk.h[2] = f2bf(a.z * f); pk.h[3] = f2bf(a.w * f);
  pk.h[4] = f2bf(b.x * f); pk.h[5] = f2bf(b.y * f);
  pk.h[6] = f2bf(b.z * f); pk.h[7] = f2bf(b.w * f);
  urow[lane] = pk.v;
  if (lane == 0) nsq[row] = s * f * f;
}

// ---- K3: GEMM dot[m][o] = sum_k u_im2col[m][k] * wt[o][k], m97-style 128x128 ----
__global__ __launch_bounds__(256) void k_gemm(const u16* __restrict__ U,
                                              const u16* __restrict__ WT,
                                              float* __restrict__ out) {
  __shared__ u16 lA[128 * 64];
  __shared__ u16 lB[128 * 64];
  int bid = blockIdx.x;
  int bm = bid >> 2, bn = bid & 3;      // 256 x 4
  int tid = threadIdx.x;
  int lane = tid & 63;
  int wid = tid >> 6;
  int wr = wid >> 1, wc = wid & 1;      // wave 64x64 sub-tile
  int wbase = tid & ~63;
  int chA = tid & 7;                    // 16B chunk within row
  f32x4 acc[4][4] = {};
  int lr = lane & 15;
  int lk = (lane >> 4) << 3;

  for (int ks = 0; ks < KIN / 64; ++ks) {
    int seg = ks >> 3;                  // which conv tap (0..2)
    int c0 = (ks & 7) << 6;             // col offset within tap
    const u16* gA = U + (size_t)(bm * 128 + seg * 16) * 512 + c0;
    const u16* gB = WT + (size_t)(bn * 128) * KIN + ks * 64;
#pragma unroll
    for (int q = 0; q < 4; ++q) {
      int row = q * 32 + (tid >> 3);
      gload16(gA + (size_t)row * 512 + chA * 8, &lA[(q * 256 + wbase) * 8]);
      gload16(gB + (size_t)row * KIN + chA * 8, &lB[(q * 256 + wbase) * 8]);
    }
    __syncthreads();
    const u16* pA = &lA[(wr * 64 + lr) * 64 + lk];
    const u16* pB = &lB[(wc * 64 + lr) * 64 + lk];
#pragma unroll
    for (int kk2 = 0; kk2 < 2; ++kk2) {
      bf16x8 af[4], bf[4];
#pragma unroll
      for (int i = 0; i < 4; ++i) {
        af[i] = *(const bf16x8*)(pA + i * 16 * 64 + kk2 * 32);
        bf[i] = *(const bf16x8*)(pB + i * 16 * 64 + kk2 * 32);
      }
#pragma unroll
      for (int mi = 0; mi < 4; ++mi)
#pragma unroll
        for (int ni = 0; ni < 4; ++ni)
          acc[mi][ni] = __builtin_amdgcn_mfma_f32_16x16x32_bf16(
              af[mi], bf[ni], acc[mi][ni], 0, 0, 0);
    }
    __syncthreads();
  }
  int orow = bm * 128 + wr * 64 + ((lane >> 4) << 2);
  int ocol = bn * 128 + wc * 64 + (lane & 15);
#pragma unroll
  for (int mi = 0; mi < 4; ++mi)
#pragma unroll
    for (int ni = 0; ni < 4; ++ni)
#pragma unroll
      for (int j = 0; j < 4; ++j)
        out[(size_t)(orow + mi * 16 + j) * COUT + (ocol + ni * 16)] = acc[mi][ni][j];
}

// ---- K4: in-place epilogue on dot rows: poincare_linear tail + project ----
__global__ __launch_bounds__(128) void k_epi(float* __restrict__ out,
                                             const float* __restrict__ nsq,
                                             const float* __restrict__ wg,
                                             const float* __restrict__ bias) {
  int m = blockIdx.x;
  int tid = threadIdx.x;                 // 128
  int lane = tid & 63, wv_ = tid >> 6;
  float un2 = nsq[m] + nsq[m + 16] + nsq[m + 32];
  float un = sqrtf(un2);
  float unc = fmaxf(un, 1e-15f);
  float th = tanhf(unc);
  float sxp = th / unc;                  // expmap0 scale (RC=1)
  float cx2 = sxp * sxp * un2;           // ||rcx||^2
  float iden = 1.f / fmaxf(1.f - cx2, 1e-15f);

  float4 dv = ((const float4*)(out + (size_t)m * COUT))[tid];
  float4 gv = ((const float4*)wg)[tid];
  float4 bv = ((const float4*)bias)[tid];
  float dot[4] = {dv.x, dv.y, dv.z, dv.w};
  float gvr[4] = {gv.x, gv.y, gv.z, gv.w};
  float bvr[4] = {bv.x, bv.y, bv.z, bv.w};
  float y[4];
#pragma unroll
  for (int e = 0; e < 4; ++e) {
    float drcr = 2.f * bvr[e];
    float ch = coshf(drcr), sh = sinhf(drcr);
    float num = 2.f * (sxp * dot[e]) * ch - (1.f + cx2) * sh;
    float z = num * iden;
    float yp = 2.f * gvr[e] * asinhf(z);
    y[e] = sinhf(yp);
  }
  float ssl = y[0]*y[0] + y[1]*y[1] + y[2]*y[2] + y[3]*y[3];
#pragma unroll
  for (int d = 1; d < 64; d <<= 1) ssl += __shfl_xor(ssl, d);
  __shared__ float red[2];
  if (lane == 0) red[wv_] = ssl;
  __syncthreads();
  float ss = red[0] + red[1];
  float denom = 1.f + sqrtf(1.f + ss);
  float nrm = fmaxf(sqrtf(ss) / denom, 1e-15f);
  float maxn = 1.0f - 4e-3f;
  float scale = (nrm > maxn) ? (maxn / nrm) : 1.f;
  float4 ov;
  ov.x = y[0] / denom * scale;
  ov.y = y[1] / denom * scale;
  ov.z = y[2] / denom * scale;
  ov.w = y[3] / denom * scale;
  ((float4*)(out + (size_t)m * COUT))[tid] = ov;
}

extern "C" void kernel_launch(void* const* d_in, const int* in_sizes, int n_in,
                              void* d_out, int out_size, void* d_ws, size_t ws_size,
                              hipStream_t stream) {
  const float* x    = (const float*)d_in[0];
  const float* wg   = (const float*)d_in[1];
  const float* wv   = (const float*)d_in[2];
  const float* bias = (const float*)d_in[3];
  float* out = (float*)d_out;

  char* ws = (char*)d_ws;
  u16*   U    = (u16*)(ws);                    // 2050*16*512 bf16 = 33,587,200 B
  float* NSQ  = (float*)(ws + 33587200);       // 32800 f32      =    131,200 B
  u16*   WT   = (u16*)(ws + 33718400);         // 512*1536 bf16  =  1,572,864 B
  float* INVN = (float*)(ws + 35291264);       // 512 f32

  double lb = (lgamma(768.0) + lgamma(0.5) - lgamma(768.5))
            - (lgamma(256.0) + lgamma(0.5) - lgamma(256.5));
  float beta_ratio = (float)exp(lb);           // beta(768,.5)/beta(256,.5)

  k_colnorm<<<COUT, 64, 0, stream>>>(wv, INVN);
  k_wt<<<dim3(KIN / 64, COUT / 64), 256, 0, stream>>>(wv, INVN, WT);
  k_logmap<<<UROWS, 64, 0, stream>>>(x, U, NSQ, beta_ratio);
  k_gemm<<<(NROWS / 128) * (COUT / 128), 256, 0, stream>>>(U, WT, out);
  k_epi<<<NROWS, 128, 0, stream>>>(out, NSQ, wg, bias);
}

// Round 3
// 144.904 us; speedup vs baseline: 1.8667x; 1.8667x over previous
//
#include <hip/hip_runtime.h>
#include <cstdint>
#include <cmath>

typedef unsigned short u16;
typedef short bf16x8 __attribute__((ext_vector_type(8)));
typedef float f32x4 __attribute__((ext_vector_type(4)));

#define T_DIM 2048
#define B_DIM 16
#define CIN 512
#define COUT 512
#define KIN 1536
#define NROWS (T_DIM * B_DIM)        /* 32768 */
#define UROWS ((T_DIM + 2) * B_DIM)  /* 32800 */

#define LOG2E 1.44269504088896f
#define LN2   0.69314718055995f

__device__ __forceinline__ float fast_exp2(float x) {
#if __has_builtin(__builtin_amdgcn_exp2f)
  return __builtin_amdgcn_exp2f(x);
#else
  return __builtin_exp2f(x);
#endif
}
__device__ __forceinline__ float fast_log2(float x) {
#if __has_builtin(__builtin_amdgcn_logf)
  return __builtin_amdgcn_logf(x);   // v_log_f32 = log2(x)
#else
  return __builtin_log2f(x);
#endif
}
__device__ __forceinline__ float fast_rcp(float x) {
  return __builtin_amdgcn_rcpf(x);
}

__device__ __forceinline__ u16 f2bf(float f) {
  unsigned u = __builtin_bit_cast(unsigned, f);
  u = (u + 0x7FFFu + ((u >> 16) & 1u)) >> 16;   // RNE
  return (u16)u;
}

typedef __attribute__((address_space(3))) unsigned int as3u32;
typedef __attribute__((address_space(1))) unsigned int as1u32;

// async global->LDS, 16B per lane; lds must be the wave-uniform base.
__device__ __forceinline__ void gload16(const u16* g, const u16* lds) {
#if __has_builtin(__builtin_amdgcn_global_load_lds)
  __builtin_amdgcn_global_load_lds((as1u32*)(uintptr_t)g,
                                   (as3u32*)(unsigned)(uintptr_t)lds, 16, 0, 0);
#else
  unsigned lane = __lane_id();
  ((uint4*)lds)[lane] = *(const uint4*)g;
#endif
}

// ---- K0: column inv-norms of weight_v [KIN, COUT] over axis 0 ----
__global__ void k_colnorm(const float* __restrict__ wv, float* __restrict__ invn) {
  int o = blockIdx.x;
  int lane = threadIdx.x;  // 64
  float s = 0.f;
#pragma unroll
  for (int r = 0; r < KIN / 64; ++r) {
    float v = wv[(size_t)(r * 64 + lane) * COUT + o];
    s += v * v;
  }
#pragma unroll
  for (int d = 1; d < 64; d <<= 1) s += __shfl_xor(s, d);
  if (lane == 0) invn[o] = 1.f / fmaxf(sqrtf(s), 1e-15f);
}

// ---- K0b: per-channel cosh/sinh of 2*bias ----
__global__ void k_chsh(const float* __restrict__ bias, float* __restrict__ ch,
                       float* __restrict__ sh) {
  int o = blockIdx.x * blockDim.x + threadIdx.x;
  if (o < COUT) {
    float d = 2.f * bias[o];
    float e = fast_exp2(d * LOG2E);
    float ie = fast_rcp(e);
    ch[o] = 0.5f * (e + ie);
    sh[o] = 0.5f * (e - ie);
  }
}

// ---- K1: W^T bf16: wt[o][i] = wv[i][o] * invn[o] ----
__global__ void k_wt(const float* __restrict__ wv, const float* __restrict__ invn,
                     u16* __restrict__ wt) {
  __shared__ float tile[64][65];
  int i0 = blockIdx.x * 64;
  int o0 = blockIdx.y * 64;
  int tx = threadIdx.x & 63, ty = threadIdx.x >> 6;  // 256 thr
  for (int r = ty; r < 64; r += 4)
    tile[r][tx] = wv[(size_t)(i0 + r) * COUT + o0 + tx];
  __syncthreads();
  for (int r = ty; r < 64; r += 4) {
    float inv = invn[o0 + r];
    wt[(size_t)(o0 + r) * KIN + i0 + tx] = f2bf(tile[tx][r] * inv);
  }
}

// ---- K2: u = logmap0(x)*BETA_RATIO -> bf16 [UROWS,512]; nsq fp32 per row ----
__global__ void k_logmap(const float* __restrict__ x, u16* __restrict__ U,
                         float* __restrict__ nsq, float beta_ratio) {
  int row = blockIdx.x;        // 0..32799 = t_pad*16 + b
  int t = row >> 4;
  int lane = threadIdx.x;      // 64
  uint4* urow = (uint4*)(U + (size_t)row * CIN);
  if (t == 0 || t == T_DIM + 1) {
    uint4 z; z.x = z.y = z.z = z.w = 0u;
    urow[lane] = z;
    if (lane == 0) nsq[row] = 0.f;
    return;
  }
  const float4* xr = (const float4*)(x + (size_t)(row - 16) * CIN);
  float4 a = xr[lane * 2];
  float4 b = xr[lane * 2 + 1];
  float s = a.x*a.x + a.y*a.y + a.z*a.z + a.w*a.w
          + b.x*b.x + b.y*b.y + b.z*b.z + b.w*b.w;
#pragma unroll
  for (int d = 1; d < 64; d <<= 1) s += __shfl_xor(s, d);
  float r = sqrtf(s);
  float yn = fmaxf(r, 1e-15f);
  float arg = fminf(yn, 1.0f - 1e-7f);
  // atanh(arg) = 0.5*ln((1+arg)/(1-arg)) via hw log2
  float at = 0.5f * LN2 * fast_log2((1.f + arg) * fast_rcp(1.f - arg));
  float f = at / yn * beta_ratio;
  union { u16 h[8]; uint4 v; } pk;
  pk.h[0] = f2bf(a.x * f); pk.h[1] = f2bf(a.y * f);
  pk.h[2] = f2bf(a.z * f); pk.h[3] = f2bf(a.w * f);
  pk.h[4] = f2bf(b.x * f); pk.h[5] = f2bf(b.y * f);
  pk.h[6] = f2bf(b.z * f); pk.h[7] = f2bf(b.w * f);
  urow[lane] = pk.v;
  if (lane == 0) nsq[row] = s * f * f;
}

// ---- K3: GEMM dot[m][o] = sum_k u_im2col[m][k] * wt[o][k], m97-style 128x128 ----
__global__ __launch_bounds__(256) void k_gemm(const u16* __restrict__ U,
                                              const u16* __restrict__ WT,
                                              float* __restrict__ out) {
  __shared__ u16 lA[128 * 64];
  __shared__ u16 lB[128 * 64];
  int bid = blockIdx.x;
  int bm = bid >> 2, bn = bid & 3;      // 256 x 4
  int tid = threadIdx.x;
  int lane = tid & 63;
  int wid = tid >> 6;
  int wr = wid >> 1, wc = wid & 1;      // wave 64x64 sub-tile
  int wbase = tid & ~63;
  int chA = tid & 7;                    // 16B chunk within row
  f32x4 acc[4][4] = {};
  int lr = lane & 15;
  int lk = (lane >> 4) << 3;

  for (int ks = 0; ks < KIN / 64; ++ks) {
    int seg = ks >> 3;                  // which conv tap (0..2)
    int c0 = (ks & 7) << 6;             // col offset within tap
    const u16* gA = U + (size_t)(bm * 128 + seg * 16) * 512 + c0;
    const u16* gB = WT + (size_t)(bn * 128) * KIN + ks * 64;
#pragma unroll
    for (int q = 0; q < 4; ++q) {
      int row = q * 32 + (tid >> 3);
      gload16(gA + (size_t)row * 512 + chA * 8, &lA[(q * 256 + wbase) * 8]);
      gload16(gB + (size_t)row * KIN + chA * 8, &lB[(q * 256 + wbase) * 8]);
    }
    __syncthreads();
    const u16* pA = &lA[(wr * 64 + lr) * 64 + lk];
    const u16* pB = &lB[(wc * 64 + lr) * 64 + lk];
#pragma unroll
    for (int kk2 = 0; kk2 < 2; ++kk2) {
      bf16x8 af[4], bf[4];
#pragma unroll
      for (int i = 0; i < 4; ++i) {
        af[i] = *(const bf16x8*)(pA + i * 16 * 64 + kk2 * 32);
        bf[i] = *(const bf16x8*)(pB + i * 16 * 64 + kk2 * 32);
      }
#pragma unroll
      for (int mi = 0; mi < 4; ++mi)
#pragma unroll
        for (int ni = 0; ni < 4; ++ni)
          acc[mi][ni] = __builtin_amdgcn_mfma_f32_16x16x32_bf16(
              af[mi], bf[ni], acc[mi][ni], 0, 0, 0);
    }
    __syncthreads();
  }
  int orow = bm * 128 + wr * 64 + ((lane >> 4) << 2);
  int ocol = bn * 128 + wc * 64 + (lane & 15);
#pragma unroll
  for (int mi = 0; mi < 4; ++mi)
#pragma unroll
    for (int ni = 0; ni < 4; ++ni)
#pragma unroll
      for (int j = 0; j < 4; ++j)
        out[(size_t)(orow + mi * 16 + j) * COUT + (ocol + ni * 16)] = acc[mi][ni][j];
}

// ---- K4: in-place epilogue on dot rows: poincare_linear tail + project ----
// All transcendentals via hw v_log_f32/v_exp_f32/v_rcp_f32:
//   sinh(2g*asinh(z)) = 0.5*(E - 1/E),  E = w^(2g),  w = z + sqrt(z^2+1)
__global__ __launch_bounds__(128) void k_epi(float* __restrict__ out,
                                             const float* __restrict__ nsq,
                                             const float* __restrict__ wg,
                                             const float* __restrict__ chv,
                                             const float* __restrict__ shv) {
  int m = blockIdx.x;
  int tid = threadIdx.x;                 // 128
  int lane = tid & 63, wv_ = tid >> 6;
  float un2 = nsq[m] + nsq[m + 16] + nsq[m + 32];
  float un = sqrtf(un2);
  float unc = fmaxf(un, 1e-15f);
  // tanh(unc) = (e2-1)/(e2+1), e2 = exp(2*unc)
  float e2 = fast_exp2(unc * (2.f * LOG2E));
  float th = (e2 - 1.f) * fast_rcp(e2 + 1.f);
  float sxp = th * fast_rcp(unc);        // expmap0 scale (RC=1)
  float cx2 = sxp * sxp * un2;           // ||rcx||^2
  float iden = fast_rcp(fmaxf(1.f - cx2, 1e-15f));

  float4 dv = ((const float4*)(out + (size_t)m * COUT))[tid];
  float4 gv = ((const float4*)wg)[tid];
  float4 cv = ((const float4*)chv)[tid];
  float4 sv = ((const float4*)shv)[tid];
  float dot[4] = {dv.x, dv.y, dv.z, dv.w};
  float gvr[4] = {gv.x, gv.y, gv.z, gv.w};
  float chr[4] = {cv.x, cv.y, cv.z, cv.w};
  float shr[4] = {sv.x, sv.y, sv.z, sv.w};
  float y[4];
  float opc = 1.f + cx2;
#pragma unroll
  for (int e = 0; e < 4; ++e) {
    float num = 2.f * (sxp * dot[e]) * chr[e] - opc * shr[e];
    float z = num * iden;
    // y = sinh(2g * asinh(z))
    float w = z + sqrtf(fmaf(z, z, 1.f));
    float l = fast_log2(w);
    float E = fast_exp2((2.f * gvr[e]) * l);
    y[e] = 0.5f * (E - fast_rcp(E));
  }
  float ssl = y[0]*y[0] + y[1]*y[1] + y[2]*y[2] + y[3]*y[3];
#pragma unroll
  for (int d = 1; d < 64; d <<= 1) ssl += __shfl_xor(ssl, d);
  __shared__ float red[2];
  if (lane == 0) red[wv_] = ssl;
  __syncthreads();
  float ss = red[0] + red[1];
  float denom = 1.f + sqrtf(1.f + ss);
  float idn = 1.f / denom;
  float nrm = fmaxf(sqrtf(ss) * idn, 1e-15f);
  float maxn = 1.0f - 4e-3f;
  float scale = (nrm > maxn) ? (maxn / nrm) : 1.f;
  scale *= idn;
  float4 ov;
  ov.x = y[0] * scale;
  ov.y = y[1] * scale;
  ov.z = y[2] * scale;
  ov.w = y[3] * scale;
  ((float4*)(out + (size_t)m * COUT))[tid] = ov;
}

extern "C" void kernel_launch(void* const* d_in, const int* in_sizes, int n_in,
                              void* d_out, int out_size, void* d_ws, size_t ws_size,
                              hipStream_t stream) {
  const float* x    = (const float*)d_in[0];
  const float* wg   = (const float*)d_in[1];
  const float* wv   = (const float*)d_in[2];
  const float* bias = (const float*)d_in[3];
  float* out = (float*)d_out;

  char* ws = (char*)d_ws;
  u16*   U    = (u16*)(ws);                    // 2050*16*512 bf16 = 33,587,200 B
  float* NSQ  = (float*)(ws + 33587200);       // 32800 f32      =    131,200 B
  u16*   WT   = (u16*)(ws + 33718400);         // 512*1536 bf16  =  1,572,864 B
  float* INVN = (float*)(ws + 35291264);       // 512 f32
  float* CH   = (float*)(ws + 35293312);       // 512 f32
  float* SH   = (float*)(ws + 35295360);       // 512 f32

  double lb = (lgamma(768.0) + lgamma(0.5) - lgamma(768.5))
            - (lgamma(256.0) + lgamma(0.5) - lgamma(256.5));
  float beta_ratio = (float)exp(lb);           // beta(768,.5)/beta(256,.5)

  k_colnorm<<<COUT, 64, 0, stream>>>(wv, INVN);
  k_chsh<<<COUT / 128, 128, 0, stream>>>(bias, CH, SH);
  k_wt<<<dim3(KIN / 64, COUT / 64), 256, 0, stream>>>(wv, INVN, WT);
  k_logmap<<<UROWS, 64, 0, stream>>>(x, U, NSQ, beta_ratio);
  k_gemm<<<(NROWS / 128) * (COUT / 128), 256, 0, stream>>>(U, WT, out);
  k_epi<<<NROWS, 128, 0, stream>>>(out, NSQ, wg, CH, SH);
}

// Round 4
// 128.716 us; speedup vs baseline: 2.1015x; 1.1258x over previous
//
#include <hip/hip_runtime.h>
#include <cstdint>
#include <cmath>

typedef unsigned short u16;
typedef short bf16x8 __attribute__((ext_vector_type(8)));
typedef float f32x4 __attribute__((ext_vector_type(4)));

#define T_DIM 2048
#define B_DIM 16
#define CIN 512
#define COUT 512
#define KIN 1536
#define NROWS (T_DIM * B_DIM)        /* 32768 */
#define UROWS ((T_DIM + 2) * B_DIM)  /* 32800 */

#define LOG2E 1.44269504088896f
#define LN2   0.69314718055995f

__device__ __forceinline__ float fast_exp2(float x) {
#if __has_builtin(__builtin_amdgcn_exp2f)
  return __builtin_amdgcn_exp2f(x);
#else
  return __builtin_exp2f(x);
#endif
}
__device__ __forceinline__ float fast_log2(float x) {
#if __has_builtin(__builtin_amdgcn_logf)
  return __builtin_amdgcn_logf(x);   // v_log_f32 = log2(x)
#else
  return __builtin_log2f(x);
#endif
}
__device__ __forceinline__ float fast_rcp(float x) {
  return __builtin_amdgcn_rcpf(x);
}

__device__ __forceinline__ u16 f2bf(float f) {
  unsigned u = __builtin_bit_cast(unsigned, f);
  u = (u + 0x7FFFu + ((u >> 16) & 1u)) >> 16;   // RNE
  return (u16)u;
}

typedef __attribute__((address_space(3))) unsigned int as3u32;
typedef __attribute__((address_space(1))) unsigned int as1u32;

// async global->LDS, 16B per lane; lds must be the wave-uniform base.
__device__ __forceinline__ void gload16(const u16* g, const u16* lds) {
#if __has_builtin(__builtin_amdgcn_global_load_lds)
  __builtin_amdgcn_global_load_lds((as1u32*)(uintptr_t)g,
                                   (as3u32*)(unsigned)(uintptr_t)lds, 16, 0, 0);
#else
  unsigned lane = __lane_id();
  ((uint4*)lds)[lane] = *(const uint4*)g;
#endif
}

// ---- K0: column inv-norms of weight_v [KIN, COUT] over axis 0 ----
__global__ void k_colnorm(const float* __restrict__ wv, float* __restrict__ invn) {
  int o = blockIdx.x;
  int lane = threadIdx.x;  // 64
  float s = 0.f;
#pragma unroll
  for (int r = 0; r < KIN / 64; ++r) {
    float v = wv[(size_t)(r * 64 + lane) * COUT + o];
    s += v * v;
  }
#pragma unroll
  for (int d = 1; d < 64; d <<= 1) s += __shfl_xor(s, d);
  if (lane == 0) invn[o] = 1.f / fmaxf(sqrtf(s), 1e-15f);
}

// ---- K0b: per-channel cosh/sinh of 2*bias ----
__global__ void k_chsh(const float* __restrict__ bias, float* __restrict__ ch,
                       float* __restrict__ sh) {
  int o = blockIdx.x * blockDim.x + threadIdx.x;
  if (o < COUT) {
    float d = 2.f * bias[o];
    float e = fast_exp2(d * LOG2E);
    float ie = fast_rcp(e);
    ch[o] = 0.5f * (e + ie);
    sh[o] = 0.5f * (e - ie);
  }
}

// ---- K1: W^T bf16: wt[o][i] = wv[i][o] * invn[o] ----
__global__ void k_wt(const float* __restrict__ wv, const float* __restrict__ invn,
                     u16* __restrict__ wt) {
  __shared__ float tile[64][65];
  int i0 = blockIdx.x * 64;
  int o0 = blockIdx.y * 64;
  int tx = threadIdx.x & 63, ty = threadIdx.x >> 6;  // 256 thr
  for (int r = ty; r < 64; r += 4)
    tile[r][tx] = wv[(size_t)(i0 + r) * COUT + o0 + tx];
  __syncthreads();
  for (int r = ty; r < 64; r += 4) {
    float inv = invn[o0 + r];
    wt[(size_t)(o0 + r) * KIN + i0 + tx] = f2bf(tile[tx][r] * inv);
  }
}

// ---- K2: u = logmap0(x)*BETA_RATIO -> bf16 [UROWS,512]; nsq fp32 per row ----
__global__ void k_logmap(const float* __restrict__ x, u16* __restrict__ U,
                         float* __restrict__ nsq, float beta_ratio) {
  int row = blockIdx.x;        // 0..32799 = t_pad*16 + b
  int t = row >> 4;
  int lane = threadIdx.x;      // 64
  uint4* urow = (uint4*)(U + (size_t)row * CIN);
  if (t == 0 || t == T_DIM + 1) {
    uint4 z; z.x = z.y = z.z = z.w = 0u;
    urow[lane] = z;
    if (lane == 0) nsq[row] = 0.f;
    return;
  }
  const float4* xr = (const float4*)(x + (size_t)(row - 16) * CIN);
  float4 a = xr[lane * 2];
  float4 b = xr[lane * 2 + 1];
  float s = a.x*a.x + a.y*a.y + a.z*a.z + a.w*a.w
          + b.x*b.x + b.y*b.y + b.z*b.z + b.w*b.w;
#pragma unroll
  for (int d = 1; d < 64; d <<= 1) s += __shfl_xor(s, d);
  float r = sqrtf(s);
  float yn = fmaxf(r, 1e-15f);
  float arg = fminf(yn, 1.0f - 1e-7f);
  // atanh(arg) = 0.5*ln((1+arg)/(1-arg)) via hw log2
  float at = 0.5f * LN2 * fast_log2((1.f + arg) * fast_rcp(1.f - arg));
  float f = at / yn * beta_ratio;
  union { u16 h[8]; uint4 v; } pk;
  pk.h[0] = f2bf(a.x * f); pk.h[1] = f2bf(a.y * f);
  pk.h[2] = f2bf(a.z * f); pk.h[3] = f2bf(a.w * f);
  pk.h[4] = f2bf(b.x * f); pk.h[5] = f2bf(b.y * f);
  pk.h[6] = f2bf(b.z * f); pk.h[7] = f2bf(b.w * f);
  urow[lane] = pk.v;
  if (lane == 0) nsq[row] = s * f * f;
}

// ---- K3: GEMM dot[m][o] = sum_k u_im2col[m][k] * wt[o][k], 128x128 tile ----
// LDS tiles [128][64]u16 have 128B rows = exact bank wrap -> naive frag reads
// are 16-way conflicted. Fix (T2, both-sides): physical chunk p = c ^ (row&7);
// reads use swizzled chunk, writes pre-swizzle the GLOBAL source chunk while
// global_load_lds LDS dests stay linear (wave base + lane*16B).
__global__ __launch_bounds__(256) void k_gemm(const u16* __restrict__ U,
                                              const u16* __restrict__ WT,
                                              float* __restrict__ out) {
  __shared__ u16 lA[128 * 64];
  __shared__ u16 lB[128 * 64];
  int bid = blockIdx.x;
  // XCD grouping: 4 bn-blocks of one bm share bid%8 -> same XCD L2.
  int bm = ((bid >> 5) << 3) | (bid & 7);
  int bn = (bid >> 3) & 3;
  int tid = threadIdx.x;
  int lane = tid & 63;
  int wid = tid >> 6;
  int wr = wid >> 1, wc = wid & 1;      // wave 64x64 sub-tile
  int wbase = tid & ~63;
  // staging: thread covers LDS row (tid>>3), phys chunk (tid&7);
  // global source chunk = (tid&7) ^ (row&7)
  int chSw = (tid & 7) ^ ((tid >> 3) & 7);
  f32x4 acc[4][4] = {};
  int lr = lane & 15;
  // fragment read phys chunk offsets (u16): p = (c | kk2*4) ^ (lr&7)
  int ph0 = (((lane >> 4)) ^ (lr & 7)) << 3;
  int ph1 = (((lane >> 4) | 4) ^ (lr & 7)) << 3;

  for (int ks = 0; ks < KIN / 64; ++ks) {
    int seg = ks >> 3;                  // which conv tap (0..2)
    int c0 = (ks & 7) << 6;             // col offset within tap
    const u16* gA = U + (size_t)(bm * 128 + seg * 16) * 512 + c0;
    const u16* gB = WT + (size_t)(bn * 128) * KIN + ks * 64;
#pragma unroll
    for (int q = 0; q < 4; ++q) {
      int row = q * 32 + (tid >> 3);
      gload16(gA + (size_t)row * 512 + chSw * 8, &lA[(q * 256 + wbase) * 8]);
      gload16(gB + (size_t)row * KIN + chSw * 8, &lB[(q * 256 + wbase) * 8]);
    }
    __syncthreads();
    const u16* pA = &lA[(wr * 64 + lr) * 64];
    const u16* pB = &lB[(wc * 64 + lr) * 64];
#pragma unroll
    for (int kk2 = 0; kk2 < 2; ++kk2) {
      int ph = kk2 ? ph1 : ph0;
      bf16x8 af[4], bf[4];
#pragma unroll
      for (int i = 0; i < 4; ++i) {
        af[i] = *(const bf16x8*)(pA + i * 16 * 64 + ph);
        bf[i] = *(const bf16x8*)(pB + i * 16 * 64 + ph);
      }
#pragma unroll
      for (int mi = 0; mi < 4; ++mi)
#pragma unroll
        for (int ni = 0; ni < 4; ++ni)
          acc[mi][ni] = __builtin_amdgcn_mfma_f32_16x16x32_bf16(
              af[mi], bf[ni], acc[mi][ni], 0, 0, 0);
    }
    __syncthreads();
  }
  int orow = bm * 128 + wr * 64 + ((lane >> 4) << 2);
  int ocol = bn * 128 + wc * 64 + (lane & 15);
#pragma unroll
  for (int mi = 0; mi < 4; ++mi)
#pragma unroll
    for (int ni = 0; ni < 4; ++ni)
#pragma unroll
      for (int j = 0; j < 4; ++j)
        out[(size_t)(orow + mi * 16 + j) * COUT + (ocol + ni * 16)] = acc[mi][ni][j];
}

// ---- K4: in-place epilogue on dot rows: poincare_linear tail + project ----
// All transcendentals via hw v_log_f32/v_exp_f32/v_rcp_f32:
//   sinh(2g*asinh(z)) = 0.5*(E - 1/E),  E = w^(2g),  w = z + sqrt(z^2+1)
__global__ __launch_bounds__(128) void k_epi(float* __restrict__ out,
                                             const float* __restrict__ nsq,
                                             const float* __restrict__ wg,
                                             const float* __restrict__ chv,
                                             const float* __restrict__ shv) {
  int m = blockIdx.x;
  int tid = threadIdx.x;                 // 128
  int lane = tid & 63, wv_ = tid >> 6;
  float un2 = nsq[m] + nsq[m + 16] + nsq[m + 32];
  float un = sqrtf(un2);
  float unc = fmaxf(un, 1e-15f);
  // tanh(unc) = (e2-1)/(e2+1), e2 = exp(2*unc)
  float e2 = fast_exp2(unc * (2.f * LOG2E));
  float th = (e2 - 1.f) * fast_rcp(e2 + 1.f);
  float sxp = th * fast_rcp(unc);        // expmap0 scale (RC=1)
  float cx2 = sxp * sxp * un2;           // ||rcx||^2
  float iden = fast_rcp(fmaxf(1.f - cx2, 1e-15f));

  float4 dv = ((const float4*)(out + (size_t)m * COUT))[tid];
  float4 gv = ((const float4*)wg)[tid];
  float4 cv = ((const float4*)chv)[tid];
  float4 sv = ((const float4*)shv)[tid];
  float dot[4] = {dv.x, dv.y, dv.z, dv.w};
  float gvr[4] = {gv.x, gv.y, gv.z, gv.w};
  float chr[4] = {cv.x, cv.y, cv.z, cv.w};
  float shr[4] = {sv.x, sv.y, sv.z, sv.w};
  float y[4];
  float opc = 1.f + cx2;
#pragma unroll
  for (int e = 0; e < 4; ++e) {
    float num = 2.f * (sxp * dot[e]) * chr[e] - opc * shr[e];
    float z = num * iden;
    // y = sinh(2g * asinh(z))
    float w = z + sqrtf(fmaf(z, z, 1.f));
    float l = fast_log2(w);
    float E = fast_exp2((2.f * gvr[e]) * l);
    y[e] = 0.5f * (E - fast_rcp(E));
  }
  float ssl = y[0]*y[0] + y[1]*y[1] + y[2]*y[2] + y[3]*y[3];
#pragma unroll
  for (int d = 1; d < 64; d <<= 1) ssl += __shfl_xor(ssl, d);
  __shared__ float red[2];
  if (lane == 0) red[wv_] = ssl;
  __syncthreads();
  float ss = red[0] + red[1];
  float denom = 1.f + sqrtf(1.f + ss);
  float idn = 1.f / denom;
  float nrm = fmaxf(sqrtf(ss) * idn, 1e-15f);
  float maxn = 1.0f - 4e-3f;
  float scale = (nrm > maxn) ? (maxn / nrm) : 1.f;
  scale *= idn;
  float4 ov;
  ov.x = y[0] * scale;
  ov.y = y[1] * scale;
  ov.z = y[2] * scale;
  ov.w = y[3] * scale;
  ((float4*)(out + (size_t)m * COUT))[tid] = ov;
}

extern "C" void kernel_launch(void* const* d_in, const int* in_sizes, int n_in,
                              void* d_out, int out_size, void* d_ws, size_t ws_size,
                              hipStream_t stream) {
  const float* x    = (const float*)d_in[0];
  const float* wg   = (const float*)d_in[1];
  const float* wv   = (const float*)d_in[2];
  const float* bias = (const float*)d_in[3];
  float* out = (float*)d_out;

  char* ws = (char*)d_ws;
  u16*   U    = (u16*)(ws);                    // 2050*16*512 bf16 = 33,587,200 B
  float* NSQ  = (float*)(ws + 33587200);       // 32800 f32      =    131,200 B
  u16*   WT   = (u16*)(ws + 33718400);         // 512*1536 bf16  =  1,572,864 B
  float* INVN = (float*)(ws + 35291264);       // 512 f32
  float* CH   = (float*)(ws + 35293312);       // 512 f32
  float* SH   = (float*)(ws + 35295360);       // 512 f32

  double lb = (lgamma(768.0) + lgamma(0.5) - lgamma(768.5))
            - (lgamma(256.0) + lgamma(0.5) - lgamma(256.5));
  float beta_ratio = (float)exp(lb);           // beta(768,.5)/beta(256,.5)

  k_colnorm<<<COUT, 64, 0, stream>>>(wv, INVN);
  k_chsh<<<COUT / 128, 128, 0, stream>>>(bias, CH, SH);
  k_wt<<<dim3(KIN / 64, COUT / 64), 256, 0, stream>>>(wv, INVN, WT);
  k_logmap<<<UROWS, 64, 0, stream>>>(x, U, NSQ, beta_ratio);
  k_gemm<<<(NROWS / 128) * (COUT / 128), 256, 0, stream>>>(U, WT, out);
  k_epi<<<NROWS, 128, 0, stream>>>(out, NSQ, wg, CH, SH);
}